// Round 3
// baseline (1756.036 us; speedup 1.0000x reference)
//
#include <hip/hip_runtime.h>

#define FDIM 128
#define NREL 8
#define BM 64
#define SCHUNK 4096

typedef __attribute__((ext_vector_type(8))) short bf16x8;
typedef __attribute__((ext_vector_type(8))) unsigned short u16x8;
typedef __attribute__((ext_vector_type(4))) float f32x4;

__device__ __forceinline__ unsigned short f2bf(float f) {
  unsigned int u = __float_as_uint(f);
  u += 0x7fffu + ((u >> 16) & 1u);   // round-to-nearest-even
  return (unsigned short)(u >> 16);
}

// ---------------- prep kernels (once; edges are layer-invariant) ----------------

__global__ void zero_u32(unsigned int* __restrict__ p, long n) {
  long i = (long)blockIdx.x * blockDim.x + threadIdx.x;
  long s = (long)gridDim.x * blockDim.x;
  for (; i < n; i += s) p[i] = 0u;
}

__global__ void hist_k(const int* __restrict__ dst, const int* __restrict__ et,
                       int E, int* __restrict__ cnt, int N) {
  int e = blockIdx.x * 256 + threadIdx.x;
  if (e < E) atomicAdd(&cnt[et[e] * N + dst[e]], 1);
}

__global__ void scan_partial(const int* __restrict__ cnt, int n, int* __restrict__ sums) {
  __shared__ int red[256];
  int base = blockIdx.x * SCHUNK;
  int s = 0;
  for (int i = threadIdx.x; i < SCHUNK; i += 256) {
    int j = base + i;
    s += (j < n) ? cnt[j] : 0;
  }
  red[threadIdx.x] = s;
  __syncthreads();
  for (int o = 128; o > 0; o >>= 1) {
    if (threadIdx.x < o) red[threadIdx.x] += red[threadIdx.x + o];
    __syncthreads();
  }
  if (threadIdx.x == 0) sums[blockIdx.x] = red[0];
}

__global__ void scan_sums(int* __restrict__ sums, int nb) {
  __shared__ int tmp[256];
  int t = threadIdx.x;
  int v = (t < nb) ? sums[t] : 0;
  tmp[t] = v;
  __syncthreads();
  for (int o = 1; o < 256; o <<= 1) {
    int u = (t >= o) ? tmp[t - o] : 0;
    __syncthreads();
    tmp[t] += u;
    __syncthreads();
  }
  if (t < nb) sums[t] = tmp[t] - v;  // exclusive
}

__global__ void scan_final(const int* __restrict__ cnt, int n,
                           const int* __restrict__ sums, int* __restrict__ off) {
  __shared__ int red[256];
  int t = threadIdx.x;
  int base = blockIdx.x * SCHUNK;
  int loc[16];
  int s = 0;
#pragma unroll
  for (int i = 0; i < 16; ++i) {
    int j = base + t * 16 + i;
    int v = (j < n) ? cnt[j] : 0;
    loc[i] = s;
    s += v;
  }
  red[t] = s;
  __syncthreads();
  int mine = s;
  for (int o = 1; o < 256; o <<= 1) {
    int u = (t >= o) ? red[t - o] : 0;
    __syncthreads();
    red[t] += u;
    __syncthreads();
  }
  int tp = red[t] - mine;
  int bb = sums[blockIdx.x];
#pragma unroll
  for (int i = 0; i < 16; ++i) {
    int j = base + t * 16 + i;
    if (j < n) off[j] = bb + tp + loc[i];
  }
}

// stable-ish scatter into sorted order; also stores dst for the fused kernel
__global__ void sort_k(const int* __restrict__ src, const int* __restrict__ dst,
                       const int* __restrict__ et, int E, int* __restrict__ cur,
                       int2* __restrict__ ssd, int N) {
  int e = blockIdx.x * 256 + threadIdx.x;
  if (e < E) {
    int d = dst[e];
    int key = et[e] * N + d;
    int p = atomicAdd(&cur[key], 1);
    ssd[p] = make_int2(src[e], d);
  }
}

// transpose {root, W0..W7} per layer into bf16 [j][k]; 27 blocks
__global__ void wtrans_k(const float* __restrict__ r1, const float* __restrict__ w1,
                         const float* __restrict__ r2, const float* __restrict__ w2,
                         const float* __restrict__ r3, const float* __restrict__ w3,
                         unsigned short* __restrict__ Wt) {
  int b = blockIdx.x;
  int L = b / 9, s = b % 9;
  const float* root = (L == 0) ? r1 : (L == 1) ? r2 : r3;
  const float* W = (L == 0) ? w1 : (L == 1) ? w2 : w3;
  const float* src = (s == 0) ? root : W + (size_t)(s - 1) * FDIM * FDIM;
  unsigned short* out = Wt + (size_t)b * FDIM * FDIM;
  for (int i = threadIdx.x; i < FDIM * FDIM; i += 256) {
    int j = i >> 7, k = i & 127;
    out[i] = f2bf(src[k * FDIM + j]);
  }
}

// ---------------- fused layer: out = relu(bias + in@root + sum_r mean_r(in)@W_r) ----
// One block = 64 output rows. Per source s (0=root, 1..8=relations):
//   - ds_write W tile (prefetched into regs one source ahead)
//   - accumulate A-tile in fp32 LDS: root = direct load; relations = contiguous
//     sorted-edge slice, edge-parallel gathers + ds_add_f32 atomics
//   - build bf16 a-frags from LDS (mean scale folded into cvt), MFMA 16x16x32
// LDS tiles XOR-swizzled in 16B units: unit_col ^ (row & 7)  (2-way max = free).
__global__ __launch_bounds__(256) void fused_layer(
    const float* __restrict__ in, const int2* __restrict__ ssd,
    const int* __restrict__ off, const unsigned short* __restrict__ Wt,
    const float* __restrict__ bias, float* __restrict__ out, int N) {
  __shared__ __align__(16) float accs[BM * FDIM];          // 32 KB fp32 A accumulate
  __shared__ __align__(16) unsigned short Bs[FDIM * FDIM]; // 32 KB bf16 W tile
  __shared__ float scl[BM];

  const int tid = threadIdx.x;
  const int wave = tid >> 6, lane = tid & 63;
  const int l16 = lane & 15, lq = lane >> 4;
  const int c4 = tid & 31, grp = tid >> 5;  // edge-phase: col-quad / edge group
  const int row0 = blockIdx.x * BM;
  const int nrows = min(BM, N - row0);

  f32x4 pacc[8];
#pragma unroll
  for (int n = 0; n < 8; ++n) pacc[n] = (f32x4){0.f, 0.f, 0.f, 0.f};

  // prefetch W tile for source 0 into registers
  u16x8 breg[8];
  {
    const u16x8* g = (const u16x8*)Wt;
#pragma unroll
    for (int i = 0; i < 8; ++i) breg[i] = g[tid + 256 * i];
  }

  for (int s = 0; s < 1 + NREL; ++s) {
    __syncthreads();  // prev iteration's LDS reads (MFMA frags) complete

    // write W tile (swizzled) from prefetch regs
#pragma unroll
    for (int i = 0; i < 8; ++i) {
      int u = tid + 256 * i;
      int r = u >> 4, kb = u & 15;
      ((u16x8*)Bs)[(r << 4) | (kb ^ (r & 7))] = breg[i];
    }
    // zero A accumulator (skipped for root: fully overwritten below)
    if (s > 0) {
#pragma unroll
      for (int i = 0; i < 8; ++i)
        ((float4*)accs)[tid + 256 * i] = make_float4(0.f, 0.f, 0.f, 0.f);
    }
    // prefetch next source's W tile
    if (s < NREL) {
      const u16x8* g = (const u16x8*)(Wt + (size_t)(s + 1) * FDIM * FDIM);
#pragma unroll
      for (int i = 0; i < 8; ++i) breg[i] = g[tid + 256 * i];
    }
    __syncthreads();  // Bs + zeroed accs visible to all

    if (s == 0) {
      // root: stage input rows directly (scale 1)
#pragma unroll
      for (int i = 0; i < 8; ++i) {
        int u = tid + 256 * i;
        int r = u >> 5, c = u & 31;
        float4 v = make_float4(0.f, 0.f, 0.f, 0.f);
        if (r < nrows) v = ((const float4*)(in + (size_t)(row0 + r) * FDIM))[c];
        ((float4*)accs)[(r << 5) | (c ^ (r & 7))] = v;
      }
    } else {
      const int rel = s - 1;
      const int key0 = rel * N + row0;
      if (tid < BM) {
        float sc = 0.f;
        if (tid < nrows) {
          int c = off[key0 + tid + 1] - off[key0 + tid];
          sc = (c > 0) ? 1.0f / (float)c : 0.f;
        }
        scl[tid] = sc;
      }
      const int ebase = off[key0];
      const int eend = off[key0 + nrows];
      // edge-parallel accumulate: group g handles edges ebase+g, +8, ...
      int e = ebase + grp;
      int2 ed;
      float4 v;
      bool have = (e < eend);
      if (have) {
        ed = ssd[e];
        v = ((const float4*)(in + (size_t)ed.x * FDIM))[c4];
      }
      while (have) {
        int e2 = e + 8;
        int2 ed2;
        float4 v2;
        bool have2 = (e2 < eend);
        if (have2) {  // prefetch next edge while current atomics retire
          ed2 = ssd[e2];
          v2 = ((const float4*)(in + (size_t)ed2.x * FDIM))[c4];
        }
        int lr = ed.y - row0;
        float* ap = &accs[(((lr << 5) | (c4 ^ (lr & 7))) << 2)];
        atomicAdd(ap + 0, v.x);
        atomicAdd(ap + 1, v.y);
        atomicAdd(ap + 2, v.z);
        atomicAdd(ap + 3, v.w);
        e = e2; ed = ed2; v = v2; have = have2;
      }
    }
    __syncthreads();  // A tile complete (+ scl)

    // MFMA phase: wave owns rows wave*16 .. wave*16+15
    const int arow = wave * 16 + l16;
    const float sc = (s == 0) ? 1.0f : scl[arow];
#pragma unroll
    for (int kk = 0; kk < 4; ++kk) {
      int cu = (kk * 4 + lq) * 2;  // float4-unit pair holding k = (kk*4+lq)*8 ..+7
      f32x4 f0 = ((const f32x4*)accs)[(arow << 5) | (cu ^ (arow & 7))];
      f32x4 f1 = ((const f32x4*)accs)[(arow << 5) | ((cu + 1) ^ (arow & 7))];
      bf16x8 a;
      a[0] = (short)f2bf(f0[0] * sc); a[1] = (short)f2bf(f0[1] * sc);
      a[2] = (short)f2bf(f0[2] * sc); a[3] = (short)f2bf(f0[3] * sc);
      a[4] = (short)f2bf(f1[0] * sc); a[5] = (short)f2bf(f1[1] * sc);
      a[6] = (short)f2bf(f1[2] * sc); a[7] = (short)f2bf(f1[3] * sc);
#pragma unroll
      for (int n = 0; n < 8; ++n) {
        int br = n * 16 + l16;
        bf16x8 b = ((const bf16x8*)Bs)[(br << 4) | ((kk * 4 + lq) ^ (br & 7))];
        pacc[n] = __builtin_amdgcn_mfma_f32_16x16x32_bf16(a, b, pacc[n], 0, 0, 0);
      }
    }
  }

  // epilogue: D layout col=lane&15, row=(lane>>4)*4+reg; bias + relu
#pragma unroll
  for (int n = 0; n < 8; ++n) {
    int col = (n << 4) | l16;
    float bv = bias[col];
#pragma unroll
    for (int rr = 0; rr < 4; ++rr) {
      int row = wave * 16 + lq * 4 + rr;
      if (row0 + row < N)
        out[(size_t)(row0 + row) * FDIM + col] = fmaxf(pacc[n][rr] + bv, 0.f);
    }
  }
}

// ---------------- host ----------------

extern "C" void kernel_launch(void* const* d_in, const int* in_sizes, int n_in,
                              void* d_out, int out_size, void* d_ws, size_t ws_size,
                              hipStream_t stream) {
  const float* x = (const float*)d_in[0];
  const int* ei = (const int*)d_in[1];
  const int* et = (const int*)d_in[2];
  const float* W[3]    = {(const float*)d_in[3], (const float*)d_in[6], (const float*)d_in[9]};
  const float* root[3] = {(const float*)d_in[4], (const float*)d_in[7], (const float*)d_in[10]};
  const float* bias[3] = {(const float*)d_in[5], (const float*)d_in[8], (const float*)d_in[11]};

  const int N = in_sizes[0] / FDIM;
  const int E = in_sizes[1] / 2;
  const int* src = ei;
  const int* dst = ei + E;
  const int NK = NREL * N;

  char* w = (char*)d_ws;
  size_t pos = 0;
  auto carve = [&](size_t bytes) -> void* {
    pos = (pos + 255) & ~(size_t)255;
    void* p = w + pos;
    pos += bytes;
    return p;
  };
  int* cnt = (int*)carve(sizeof(int) * (NK + 1));
  int* off = (int*)carve(sizeof(int) * (NK + 1));
  int* cur = (int*)carve(sizeof(int) * (NK + 1));
  int* sums = (int*)carve(sizeof(int) * 512);
  int2* ssd = (int2*)carve(sizeof(int2) * E);
  unsigned short* Wt = (unsigned short*)carve(sizeof(unsigned short) * 27 * FDIM * FDIM);
  float* h1 = (float*)carve(sizeof(float) * (size_t)N * FDIM);
  float* h2 = (float*)carve(sizeof(float) * (size_t)N * FDIM);

  // ---- one-time edge prep: counting sort by key = rel*N + dst ----
  zero_u32<<<1024, 256, 0, stream>>>((unsigned int*)cnt, NK + 1);
  hist_k<<<(E + 255) / 256, 256, 0, stream>>>(dst, et, E, cnt, N);
  const int n_scan = NK + 1;
  const int nchunk = (n_scan + SCHUNK - 1) / SCHUNK;
  scan_partial<<<nchunk, 256, 0, stream>>>(cnt, n_scan, sums);
  scan_sums<<<1, 256, 0, stream>>>(sums, nchunk);
  scan_final<<<nchunk, 256, 0, stream>>>(cnt, n_scan, sums, off);
  hipMemcpyAsync(cur, off, sizeof(int) * NK, hipMemcpyDeviceToDevice, stream);
  sort_k<<<(E + 255) / 256, 256, 0, stream>>>(src, dst, et, E, cur, ssd, N);
  wtrans_k<<<27, 256, 0, stream>>>(root[0], W[0], root[1], W[1], root[2], W[2], Wt);

  // ---- 3 fused layers ----
  const int NB = (N + BM - 1) / BM;
  const float* in_p = x;
  float* outs[3] = {h1, h2, (float*)d_out};
  for (int L = 0; L < 3; ++L) {
    const unsigned short* WtL = Wt + (size_t)L * 9 * FDIM * FDIM;
    fused_layer<<<NB, 256, 0, stream>>>(in_p, ssd, off, WtL, bias[L], outs[L], N);
    in_p = outs[L];
  }
}